// Round 9
// baseline (203.879 us; speedup 1.0000x reference)
//
#include <hip/hip_runtime.h>
#include <math.h>

// EdgeConv, factorized:
//   A[i] = x[i] @ (W1_top - W1_bot) + b1        (64-dim f16, per node)
//   B[j] = x[j] @ W1_bot                        (64-dim bf16, per node)
//   agg1[i] = sum_{e: dst=i} relu(A[i] + B[src_e])
//   out[i]  = tanh(agg1[i] @ W2 + deg_i * b2)
//
// R8 -> R9 (prep_k only): R7's transpose "fix" scattered the x reads
// (64 lines/wave-instr). Now: coalesced float4 global reads + stride-65
// LDS rows (scalar writes/reads, 2-way banks = free), W1 tile f16
// (pre-branch LDS 50->33.5 KB => 4 blocks/CU), bin EPB 8192, 10:1 mix.
// fused_agg unchanged from R8.

#define FDIM 64
#define BN 128            // nodes per bucket
#define BSH 7             // log2(BN)
#define CAPB 2048         // bucket capacity (mean 1536, +13 sigma)
#define MAXB 1024         // LDS bucket-counter array bound in bin branch
#define EPB 8192          // edges per bin block
#define XS_S 65           // xsT row stride (words): odd -> conflict-free
#define PRE_SMEM 34048    // bytes: Wch 16896 + xsT 16640 (> bin 8192)

typedef unsigned int u32;
typedef unsigned short u16;
typedef _Float16 hf;

__device__ __forceinline__ float bf_lo(u32 u) {
    union { u32 i; float f; } c; c.i = u << 16; return c.f;
}
__device__ __forceinline__ float bf_hi(u32 u) {
    union { u32 i; float f; } c; c.i = u & 0xffff0000u; return c.f;
}
__device__ __forceinline__ u32 f2bf_rne(float f) {
    union { float f; u32 u; } c; c.f = f;
    u32 u = c.u;
    u += 0x7fffu + ((u >> 16) & 1u);   // round-to-nearest-even
    return u >> 16;
}
__device__ __forceinline__ u32 f2h(float f) {
    union { u16 s; hf h; } c; c.h = (hf)f; return (u32)c.s;
}
__device__ __forceinline__ float h_lo(u32 u) {
    union { u16 s; hf h; } c; c.s = (u16)(u & 0xffffu); return (float)c.h;
}
__device__ __forceinline__ float h_hi(u32 u) {
    union { u16 s; hf h; } c; c.s = (u16)(u >> 16); return (float)c.h;
}

// ---------------------------------------------------------------------------
// Kernel 1: merged prep.  blockIdx%11==10 -> bin branch, else node_pre.
// ---------------------------------------------------------------------------
__global__ __launch_bounds__(256) void prep_k(
    const float* __restrict__ x, const float* __restrict__ W1,
    const float* __restrict__ b1, u16* __restrict__ Ah,
    u16* __restrict__ Bmh, const int* __restrict__ ei,
    u32* __restrict__ slotB, int* __restrict__ gcnt,
    int N, int E, int NB, int nPre, int nBin)
{
    __shared__ __align__(16) char smem[PRE_SMEM];
    const int idx = blockIdx.x;
    const int tid = threadIdx.x;

    if ((idx % 11) == 10) {
        // ---------------- bin branch ----------------
        const int bb = idx / 11;
        if (bb >= nBin) return;
        int* histL = (int*)smem;
        int* gbase = histL + MAXB;
        const int e0 = bb * EPB;

        for (int j = tid; j < NB; j += 256) histL[j] = 0;
        __syncthreads();

        #pragma unroll
        for (int i = 0; i < EPB / 256; ++i) {
            int e = e0 + i * 256 + tid;
            if (e < E) {
                int d = ei[E + e];
                atomicAdd(&histL[d >> BSH], 1);
            }
        }
        __syncthreads();

        for (int j = tid; j < NB; j += 256) {
            int h = histL[j];
            gbase[j] = (h > 0) ? atomicAdd(&gcnt[j], h) : 0;
            histL[j] = 0;                 // reuse as local append pos
        }
        __syncthreads();

        #pragma unroll
        for (int i = 0; i < EPB / 256; ++i) {
            int e = e0 + i * 256 + tid;
            if (e < E) {
                int s = ei[e];
                int d = ei[E + e];
                int b = d >> BSH;
                int pos = gbase[b] + atomicAdd(&histL[b], 1);
                if (pos < CAPB)
                    slotB[(size_t)b * CAPB + pos] =
                        ((u32)(d & (BN - 1)) << 20) | (u32)s;
            }
        }
        return;
    }

    // ---------------- node_pre branch ----------------
    const int pb = idx - idx / 11;
    if (pb >= nPre) return;
    u32 (*Wch)[64] = (u32(*)[64])smem;                   // 64x64 u32 = 16384 B
    float* xsT = (float*)(smem + 64 * 64 * 4 + 512);     // 64 rows x 65 words

    const int node0 = pb * 64;

    // Stage W1 -> f16 pairs. Row k: slots 0..31 = A-weights (W1t-W1b) cols
    // 2p,2p+1; slots 32..63 = B-weights (W1b) cols 2(p-32),2(p-32)+1.
    for (int i = tid; i < 64 * 64; i += 256) {
        int k = i >> 6, p = i & 63;
        u32 pk;
        if (p < 32) {
            int c = p * 2;
            float a0 = W1[k * 64 + c]     - W1[(64 + k) * 64 + c];
            float a1 = W1[k * 64 + c + 1] - W1[(64 + k) * 64 + c + 1];
            pk = f2h(a0) | (f2h(a1) << 16);
        } else {
            int c = (p - 32) * 2;
            float v0 = W1[(64 + k) * 64 + c];
            float v1 = W1[(64 + k) * 64 + c + 1];
            pk = f2h(v0) | (f2h(v1) << 16);
        }
        Wch[k][p] = pk;
    }
    // Stage x: coalesced float4 reads; transposed scalar writes, stride-65
    // rows -> banks (4*k4+j+n)%32 all distinct pairs -> 2-way = free.
    {
        const float4* X4 = (const float4*)x;
        #pragma unroll
        for (int it = 0; it < 4; ++it) {
            int i = it * 256 + tid;            // 0..1023
            int n = i >> 4, k4 = i & 15;
            int gn = node0 + n;
            float4 v = make_float4(0.f, 0.f, 0.f, 0.f);
            if (gn < N) v = X4[(size_t)gn * 16 + k4];
            int kb = k4 * 4;
            xsT[(kb + 0) * XS_S + n] = v.x;
            xsT[(kb + 1) * XS_S + n] = v.y;
            xsT[(kb + 2) * XS_S + n] = v.z;
            xsT[(kb + 3) * XS_S + n] = v.w;
        }
    }
    __syncthreads();

    const int ng = tid & 15, cg = tid >> 4;
    const int n0 = ng * 4, c0 = cg * 8;
    const int wbase = (cg & 7) * 4 + ((cg >> 3) * 32);

    float acc[4][8];
    #pragma unroll
    for (int ci = 0; ci < 8; ++ci) {
        float init = (c0 + ci < 64) ? b1[c0 + ci] : 0.f;
        #pragma unroll
        for (int ni = 0; ni < 4; ++ni) acc[ni][ci] = init;
    }

    #pragma unroll 4
    for (int k = 0; k < 64; ++k) {
        float xs[4];
        #pragma unroll
        for (int j = 0; j < 4; ++j) xs[j] = xsT[k * XS_S + n0 + j];
        uint2 w01 = *(const uint2*)&Wch[k][wbase];
        uint2 w23 = *(const uint2*)&Wch[k][wbase + 2];
        float ws[8] = {h_lo(w01.x), h_hi(w01.x), h_lo(w01.y), h_hi(w01.y),
                       h_lo(w23.x), h_hi(w23.x), h_lo(w23.y), h_hi(w23.y)};
        #pragma unroll
        for (int ni = 0; ni < 4; ++ni)
            #pragma unroll
            for (int ci = 0; ci < 8; ++ci)
                acc[ni][ci] += xs[ni] * ws[ci];
    }

    #pragma unroll
    for (int ni = 0; ni < 4; ++ni) {
        int n = node0 + n0 + ni;
        if (n >= N) break;
        if (c0 < 64) {
            uint4 pk;
            pk.x = f2h(acc[ni][0]) | (f2h(acc[ni][1]) << 16);
            pk.y = f2h(acc[ni][2]) | (f2h(acc[ni][3]) << 16);
            pk.z = f2h(acc[ni][4]) | (f2h(acc[ni][5]) << 16);
            pk.w = f2h(acc[ni][6]) | (f2h(acc[ni][7]) << 16);
            *(uint4*)&Ah[(size_t)n * 64 + c0] = pk;
        } else {
            uint4 pk;
            pk.x = f2bf_rne(acc[ni][0]) | (f2bf_rne(acc[ni][1]) << 16);
            pk.y = f2bf_rne(acc[ni][2]) | (f2bf_rne(acc[ni][3]) << 16);
            pk.z = f2bf_rne(acc[ni][4]) | (f2bf_rne(acc[ni][5]) << 16);
            pk.w = f2bf_rne(acc[ni][6]) | (f2bf_rne(acc[ni][7]) << 16);
            *(uint4*)&Bmh[(size_t)n * 64 + (c0 - 64)] = pk;
        }
    }
}

// ---------------------------------------------------------------------------
// Kernel 2: per-bucket CSR build + aggregate + W2 GEMM + tanh.
// (unchanged from R8: W2 f16 in LDS, 8-wide gather batches)
// ---------------------------------------------------------------------------
__device__ __forceinline__ float4 relu4add(float4 acc, float4 a, float4 b) {
    acc.x += fmaxf(a.x + b.x, 0.f);
    acc.y += fmaxf(a.y + b.y, 0.f);
    acc.z += fmaxf(a.z + b.z, 0.f);
    acc.w += fmaxf(a.w + b.w, 0.f);
    return acc;
}
__device__ __forceinline__ float4 relu4add_m(float4 acc, float4 a, float4 b, bool m) {
    acc.x += m ? fmaxf(a.x + b.x, 0.f) : 0.f;
    acc.y += m ? fmaxf(a.y + b.y, 0.f) : 0.f;
    acc.z += m ? fmaxf(a.z + b.z, 0.f) : 0.f;
    acc.w += m ? fmaxf(a.w + b.w, 0.f) : 0.f;
    return acc;
}
__device__ __forceinline__ float4 bf4(uint2 u) {
    return make_float4(bf_lo(u.x), bf_hi(u.x), bf_lo(u.y), bf_hi(u.y));
}

__global__ __launch_bounds__(256) void fused_agg(
    const u16* __restrict__ Ah, const u16* __restrict__ Bmh,
    const u32* __restrict__ slotB, const int* __restrict__ gcnt,
    const float* __restrict__ W2, const float* __restrict__ b2,
    float* __restrict__ out, int N)
{
    __shared__ __align__(16) u32 W2h[64][34];        // f16-packed W2, 8.7 KB
    __shared__ __align__(16) u32 pool[BN * 17 * 2];  // 17.4 KB: eStage then aggTb
    __shared__ u32 csrS[CAPB];                       // 8 KB
    __shared__ int histL[BN];
    __shared__ int rowO[BN + 1];
    __shared__ int ofs[BN];
    __shared__ float b2s[64];

    u32* eStage = pool;                              // [CAPB] (phase: CSR build)
    uint2* aggTb = (uint2*)pool;                     // [BN][17] (phase: agg)

    const int tid = threadIdx.x;
    const int b = blockIdx.x;
    const int node0 = b * BN;
    const int cntB = min(gcnt[b], CAPB);

    for (int i = tid; i < 1024; i += 256) {
        int k = i >> 4, c4 = (i & 15) * 4;
        float4 w = *(const float4*)&W2[k * 64 + c4];
        uint2 pk;
        pk.x = f2h(w.x) | (f2h(w.y) << 16);
        pk.y = f2h(w.z) | (f2h(w.w) << 16);
        *(uint2*)&W2h[k][c4 >> 1] = pk;
    }
    if (tid < 64) b2s[tid] = b2[tid];
    if (tid < BN) histL[tid] = 0;
    __syncthreads();

    for (int i = tid; i < cntB; i += 256) {
        u32 e = slotB[(size_t)b * CAPB + i];
        eStage[i] = e;
        atomicAdd(&histL[e >> 20], 1);
    }
    __syncthreads();

    if (tid < 64) {                                  // exclusive scan of 128 bins
        int l = tid;
        int h0 = histL[2 * l], h1 = histL[2 * l + 1];
        int s = h0 + h1, inc = s;
        #pragma unroll
        for (int off = 1; off < 64; off <<= 1) {
            int t = __shfl_up(inc, off);
            if (l >= off) inc += t;
        }
        int base = inc - s;
        rowO[2 * l] = base; rowO[2 * l + 1] = base + h0;
        ofs[2 * l] = base;  ofs[2 * l + 1] = base + h0;
        if (l == 63) rowO[BN] = inc;
    }
    __syncthreads();

    for (int i = tid; i < cntB; i += 256) {
        u32 e = eStage[i];
        int pos = atomicAdd(&ofs[e >> 20], 1);
        csrS[pos] = e & 0xFFFFFu;
    }
    __syncthreads();                                 // eStage dead; aggTb live

    // ---- Phase 1: gather-aggregate, 8 independent gathers per round ----
    {
        const int q = tid & 15, ng = tid >> 4;
        const uint2* __restrict__ B2 = (const uint2*)Bmh;
        const uint2* __restrict__ A2 = (const uint2*)Ah;
        #pragma unroll
        for (int h = 0; h < 8; ++h) {
            int nl = ng + h * 16;
            int gn = node0 + nl;
            int start = rowO[nl];
            int d = (gn < N) ? (rowO[nl + 1] - start) : 0;
            float4 a = make_float4(0.f, 0.f, 0.f, 0.f);
            if (gn < N) {
                uint2 ua = A2[(size_t)gn * 16 + q];
                a = make_float4(h_lo(ua.x), h_hi(ua.x), h_lo(ua.y), h_hi(ua.y));
            }
            float4 acc = make_float4(0.f, 0.f, 0.f, 0.f);

            int j = 0;
            for (; j + 8 <= d; j += 8) {             // exact 8-batches
                int ss[8];
                uint2 bb[8];
                #pragma unroll
                for (int t = 0; t < 8; ++t) ss[t] = csrS[start + j + t];
                #pragma unroll
                for (int t = 0; t < 8; ++t) bb[t] = B2[(size_t)ss[t] * 16 + q];
                #pragma unroll
                for (int t = 0; t < 8; ++t) acc = relu4add(acc, a, bf4(bb[t]));
            }
            if (j < d) {                             // masked 8-tail (clamped idx)
                int ss[8];
                uint2 bb[8];
                #pragma unroll
                for (int t = 0; t < 8; ++t) ss[t] = csrS[start + min(j + t, d - 1)];
                #pragma unroll
                for (int t = 0; t < 8; ++t) bb[t] = B2[(size_t)ss[t] * 16 + q];
                acc = relu4add(acc, a, bf4(bb[0]));
                #pragma unroll
                for (int t = 1; t < 8; ++t)
                    acc = relu4add_m(acc, a, bf4(bb[t]), j + t < d);
            }
            uint2 pk;
            pk.x = f2h(acc.x) | (f2h(acc.y) << 16);
            pk.y = f2h(acc.z) | (f2h(acc.w) << 16);
            aggTb[nl * 17 + q] = pk;
        }
    }
    __syncthreads();

    // ---- Phase 2: [128x64] @ W2 + deg*b2, tanh; W2 f16 from LDS ----
    {
        const int cg = tid & 15, g0 = tid >> 4;
        const int c0 = cg * 4;
        #pragma unroll
        for (int h = 0; h < 2; ++h) {
            int g = g0 + h * 16;       // 0..31
            int nb0 = g * 4;           // nodes nb0..nb0+3
            float o[4][4];
            #pragma unroll
            for (int ni = 0; ni < 4; ++ni) {
                float dg = (float)(rowO[nb0 + ni + 1] - rowO[nb0 + ni]);
                #pragma unroll
                for (int ci = 0; ci < 4; ++ci) o[ni][ci] = dg * b2s[c0 + ci];
            }
            #pragma unroll 2
            for (int kc = 0; kc < 16; ++kc) {
                uint2 u0 = aggTb[(nb0 + 0) * 17 + kc];
                uint2 u1 = aggTb[(nb0 + 1) * 17 + kc];
                uint2 u2 = aggTb[(nb0 + 2) * 17 + kc];
                uint2 u3 = aggTb[(nb0 + 3) * 17 + kc];
                #pragma unroll
                for (int kk = 0; kk < 4; ++kk) {
                    uint2 w2p = *(const uint2*)&W2h[kc * 4 + kk][cg * 2];
                    float wv[4] = {h_lo(w2p.x), h_hi(w2p.x), h_lo(w2p.y), h_hi(w2p.y)};
                    float a0 = (kk < 2) ? ((kk == 0) ? h_lo(u0.x) : h_hi(u0.x))
                                        : ((kk == 2) ? h_lo(u0.y) : h_hi(u0.y));
                    float a1 = (kk < 2) ? ((kk == 0) ? h_lo(u1.x) : h_hi(u1.x))
                                        : ((kk == 2) ? h_lo(u1.y) : h_hi(u1.y));
                    float a2 = (kk < 2) ? ((kk == 0) ? h_lo(u2.x) : h_hi(u2.x))
                                        : ((kk == 2) ? h_lo(u2.y) : h_hi(u2.y));
                    float a3 = (kk < 2) ? ((kk == 0) ? h_lo(u3.x) : h_hi(u3.x))
                                        : ((kk == 2) ? h_lo(u3.y) : h_hi(u3.y));
                    #pragma unroll
                    for (int ci = 0; ci < 4; ++ci) {
                        o[0][ci] += a0 * wv[ci];
                        o[1][ci] += a1 * wv[ci];
                        o[2][ci] += a2 * wv[ci];
                        o[3][ci] += a3 * wv[ci];
                    }
                }
            }
            #pragma unroll
            for (int ni = 0; ni < 4; ++ni) {
                int gn = node0 + nb0 + ni;
                if (gn < N) {
                    float4 r = make_float4(tanhf(o[ni][0]), tanhf(o[ni][1]),
                                           tanhf(o[ni][2]), tanhf(o[ni][3]));
                    ((float4*)out)[(size_t)gn * 16 + cg] = r;
                }
            }
        }
    }
}

// ---------------------------------------------------------------------------
extern "C" void kernel_launch(void* const* d_in, const int* in_sizes, int n_in,
                              void* d_out, int out_size, void* d_ws, size_t ws_size,
                              hipStream_t stream)
{
    const float* x  = (const float*)d_in[0];
    const int*   ei = (const int*)d_in[1];     // [2,E]: row0=src, row1=dst
    const float* W1 = (const float*)d_in[2];   // [128,64]
    const float* b1 = (const float*)d_in[3];   // [64]
    const float* W2 = (const float*)d_in[4];   // [64,64]
    const float* b2 = (const float*)d_in[5];   // [64]
    float* out = (float*)d_out;

    const int N = in_sizes[0] / FDIM;          // 100000
    const int E = in_sizes[1] / 2;             // 1200000
    const int NB = (N + BN - 1) / BN;          // 782 buckets

    // Workspace (re-poisoned 0xAA every call; gcnt zeroed below):
    u16*   Ah    = (u16*)d_ws;                          // N*64 f16  = 12.8 MB
    u16*   Bmh   = Ah + (size_t)N * FDIM;               // N*64 bf16 = 12.8 MB
    u32*   slotB = (u32*)(Bmh + (size_t)N * FDIM);      // NB*CAPB u32 = 6.4 MB
    int*   gcnt  = (int*)(slotB + (size_t)NB * CAPB);   // NB i32

    hipMemsetAsync(gcnt, 0, (size_t)NB * sizeof(int), stream);

    // Interleaved heterogeneous grid: 1 bin block per 11 (idx%11==10).
    const int nPre = (N + 63) / 64;            // 1563
    const int nBin = (E + EPB - 1) / EPB;      // 147
    int T = (nPre * 11 + 9) / 10;
    while (T - T / 11 < nPre) ++T;
    if (T / 11 < nBin) T = 11 * nBin;

    prep_k<<<T, 256, 0, stream>>>(x, W1, b1, Ah, Bmh, ei, slotB, gcnt,
                                  N, E, NB, nPre, nBin);
    fused_agg<<<NB, 256, 0, stream>>>(Ah, Bmh, slotB, gcnt, W2, b2, out, N);
}

// Round 10
// 195.323 us; speedup vs baseline: 1.0438x; 1.0438x over previous
//
#include <hip/hip_runtime.h>
#include <math.h>

// EdgeConv, factorized:
//   A[i] = x[i] @ (W1_top - W1_bot) + b1        (64-dim f16, per node)
//   B[j] = x[j] @ W1_bot                        (64-dim bf16, per node)
//   agg1[i] = sum_{e: dst=i} relu(A[i] + B[src_e])
//   out[i]  = tanh(agg1[i] @ W2 + deg_i * b2)
//
// R9 -> R10: prep MLP was LDS-issue bound (384 LDS reads/thread) and every
// block re-converted W1/W2 to f16.  Now: wprep_k converts weights ONCE to
// global f16 (Wch 16 KB, W2h 8 KB); prep stages them via uint4; x-tile is
// f16-packed (xs[64][33] u32, odd stride -> 2-way banks = free) and W is
// one ds_read_b128 per k -> 192 LDS reads/thread; pre-branch LDS 24.8 KB
// -> 6 blocks/CU.  bin reverted to EPB 4096 / 6:1.  fused_agg: W2 staged
// from precomputed f16.

#define FDIM 64
#define BN 128            // nodes per bucket
#define BSH 7             // log2(BN)
#define CAPB 2048         // bucket capacity (mean 1536, +13 sigma)
#define MAXB 1024         // LDS bucket-counter array bound in bin branch
#define EPB 4096          // edges per bin block
#define XS_W 33           // xs row stride in u32 (odd -> conflict-free)
#define PRE_SMEM 24832    // bytes: Wch 16384 + xs 8448  (> bin 8192)

typedef unsigned int u32;
typedef unsigned short u16;
typedef _Float16 hf;

__device__ __forceinline__ float bf_lo(u32 u) {
    union { u32 i; float f; } c; c.i = u << 16; return c.f;
}
__device__ __forceinline__ float bf_hi(u32 u) {
    union { u32 i; float f; } c; c.i = u & 0xffff0000u; return c.f;
}
__device__ __forceinline__ u32 f2bf_rne(float f) {
    union { float f; u32 u; } c; c.f = f;
    u32 u = c.u;
    u += 0x7fffu + ((u >> 16) & 1u);   // round-to-nearest-even
    return u >> 16;
}
__device__ __forceinline__ u32 f2h(float f) {
    union { u16 s; hf h; } c; c.h = (hf)f; return (u32)c.s;
}
__device__ __forceinline__ float h_lo(u32 u) {
    union { u16 s; hf h; } c; c.s = (u16)(u & 0xffffu); return (float)c.h;
}
__device__ __forceinline__ float h_hi(u32 u) {
    union { u16 s; hf h; } c; c.s = (u16)(u >> 16); return (float)c.h;
}

// ---------------------------------------------------------------------------
// Kernel 0: one-time weight conversion (1 block).
// Wchg[k][p] u32: p<32 -> f16 pair of (W1t-W1b)[k][2p,2p+1]; p>=32 -> W1b.
// W2hg[k*8 + q] uint-packed rows of f16(W2).
// ---------------------------------------------------------------------------
__global__ __launch_bounds__(256) void wprep_k(
    const float* __restrict__ W1, const float* __restrict__ W2,
    u32* __restrict__ Wchg, u32* __restrict__ W2hg)
{
    const int tid = threadIdx.x;
    for (int i = tid; i < 4096; i += 256) {
        int k = i >> 6, p = i & 63;
        u32 pk;
        if (p < 32) {
            int c = p * 2;
            float a0 = W1[k * 64 + c]     - W1[(64 + k) * 64 + c];
            float a1 = W1[k * 64 + c + 1] - W1[(64 + k) * 64 + c + 1];
            pk = f2h(a0) | (f2h(a1) << 16);
        } else {
            int c = (p - 32) * 2;
            pk = f2h(W1[(64 + k) * 64 + c]) | (f2h(W1[(64 + k) * 64 + c + 1]) << 16);
        }
        Wchg[i] = pk;
    }
    for (int i = tid; i < 2048; i += 256) {
        int k = i >> 5, c2 = i & 31;
        W2hg[i] = f2h(W2[k * 64 + c2 * 2]) | (f2h(W2[k * 64 + c2 * 2 + 1]) << 16);
    }
}

// ---------------------------------------------------------------------------
// Kernel 1: merged prep.  blockIdx%6==5 -> bin branch, else node_pre.
// ---------------------------------------------------------------------------
__global__ __launch_bounds__(256) void prep_k(
    const float* __restrict__ x, const u32* __restrict__ Wchg,
    const float* __restrict__ b1, u16* __restrict__ Ah,
    u16* __restrict__ Bmh, const int* __restrict__ ei,
    u32* __restrict__ slotB, int* __restrict__ gcnt,
    int N, int E, int NB, int nPre, int nBin)
{
    __shared__ __align__(16) char smem[PRE_SMEM];
    const int idx = blockIdx.x;
    const int tid = threadIdx.x;

    if ((idx % 6) == 5) {
        // ---------------- bin branch ----------------
        const int bb = idx / 6;
        if (bb >= nBin) return;
        int* histL = (int*)smem;
        int* gbase = histL + MAXB;
        const int e0 = bb * EPB;

        for (int j = tid; j < NB; j += 256) histL[j] = 0;
        __syncthreads();

        #pragma unroll
        for (int i = 0; i < EPB / 256; ++i) {
            int e = e0 + i * 256 + tid;
            if (e < E) {
                int d = ei[E + e];
                atomicAdd(&histL[d >> BSH], 1);
            }
        }
        __syncthreads();

        for (int j = tid; j < NB; j += 256) {
            int h = histL[j];
            gbase[j] = (h > 0) ? atomicAdd(&gcnt[j], h) : 0;
            histL[j] = 0;                 // reuse as local append pos
        }
        __syncthreads();

        #pragma unroll
        for (int i = 0; i < EPB / 256; ++i) {
            int e = e0 + i * 256 + tid;
            if (e < E) {
                int s = ei[e];
                int d = ei[E + e];
                int b = d >> BSH;
                int pos = gbase[b] + atomicAdd(&histL[b], 1);
                if (pos < CAPB)
                    slotB[(size_t)b * CAPB + pos] =
                        ((u32)(d & (BN - 1)) << 20) | (u32)s;
            }
        }
        return;
    }

    // ---------------- node_pre branch ----------------
    const int pb = idx - idx / 6;
    if (pb >= nPre) return;
    u32 (*Wch)[64] = (u32(*)[64])smem;                   // 16384 B
    u32* xs = (u32*)(smem + 16384);                      // 64 rows x 33 u32

    const int node0 = pb * 64;

    // Stage precomputed weights: 4 uint4 per thread, conflict-free writes.
    {
        const uint4* Wg4 = (const uint4*)Wchg;
        #pragma unroll
        for (int it = 0; it < 4; ++it) {
            int i = it * 256 + tid;            // 0..1023
            uint4 w = Wg4[i];
            *(uint4*)&Wch[i >> 4][(i & 15) * 4] = w;
        }
    }
    // Stage x: coalesced float4 reads; f16-pack; 2 u32 writes/load.
    // Write banks: (33n + 2k4)%32 = (n + 2k4)%32 -> 2-way = free.
    {
        const float4* X4 = (const float4*)x;
        #pragma unroll
        for (int it = 0; it < 4; ++it) {
            int i = it * 256 + tid;            // 0..1023
            int n = i >> 4, k4 = i & 15;
            int gn = node0 + n;
            float4 v = make_float4(0.f, 0.f, 0.f, 0.f);
            if (gn < N) v = X4[(size_t)gn * 16 + k4];
            xs[n * XS_W + 2 * k4]     = f2h(v.x) | (f2h(v.y) << 16);
            xs[n * XS_W + 2 * k4 + 1] = f2h(v.z) | (f2h(v.w) << 16);
        }
    }
    __syncthreads();

    const int ng = tid & 15, cg = tid >> 4;
    const int n0 = ng * 4, c0 = cg * 8;
    const int wbase = (cg & 7) * 4 + ((cg >> 3) * 32);   // uint4-aligned

    float acc[4][8];
    #pragma unroll
    for (int ci = 0; ci < 8; ++ci) {
        float init = b1[(c0 + ci) & 63];
        if (c0 >= 64) init = 0.f;
        #pragma unroll
        for (int ni = 0; ni < 4; ++ni) acc[ni][ci] = init;
    }

    // k-loop in pairs: per kk one u32 per node (2 k's) + 2 b128 W reads.
    #pragma unroll 4
    for (int kk = 0; kk < 32; ++kk) {
        u32 xv[4];
        #pragma unroll
        for (int ni = 0; ni < 4; ++ni) xv[ni] = xs[(n0 + ni) * XS_W + kk];
        uint4 w0 = *(const uint4*)&Wch[2 * kk][wbase];
        uint4 w1 = *(const uint4*)&Wch[2 * kk + 1][wbase];
        float ws0[8] = {h_lo(w0.x), h_hi(w0.x), h_lo(w0.y), h_hi(w0.y),
                        h_lo(w0.z), h_hi(w0.z), h_lo(w0.w), h_hi(w0.w)};
        float ws1[8] = {h_lo(w1.x), h_hi(w1.x), h_lo(w1.y), h_hi(w1.y),
                        h_lo(w1.z), h_hi(w1.z), h_lo(w1.w), h_hi(w1.w)};
        #pragma unroll
        for (int ni = 0; ni < 4; ++ni) {
            float xa = h_lo(xv[ni]);
            float xb = h_hi(xv[ni]);
            #pragma unroll
            for (int ci = 0; ci < 8; ++ci)
                acc[ni][ci] += xa * ws0[ci] + xb * ws1[ci];
        }
    }

    #pragma unroll
    for (int ni = 0; ni < 4; ++ni) {
        int n = node0 + n0 + ni;
        if (n >= N) break;
        if (c0 < 64) {
            uint4 pk;
            pk.x = f2h(acc[ni][0]) | (f2h(acc[ni][1]) << 16);
            pk.y = f2h(acc[ni][2]) | (f2h(acc[ni][3]) << 16);
            pk.z = f2h(acc[ni][4]) | (f2h(acc[ni][5]) << 16);
            pk.w = f2h(acc[ni][6]) | (f2h(acc[ni][7]) << 16);
            *(uint4*)&Ah[(size_t)n * 64 + c0] = pk;
        } else {
            uint4 pk;
            pk.x = f2bf_rne(acc[ni][0]) | (f2bf_rne(acc[ni][1]) << 16);
            pk.y = f2bf_rne(acc[ni][2]) | (f2bf_rne(acc[ni][3]) << 16);
            pk.z = f2bf_rne(acc[ni][4]) | (f2bf_rne(acc[ni][5]) << 16);
            pk.w = f2bf_rne(acc[ni][6]) | (f2bf_rne(acc[ni][7]) << 16);
            *(uint4*)&Bmh[(size_t)n * 64 + (c0 - 64)] = pk;
        }
    }
}

// ---------------------------------------------------------------------------
// Kernel 2: per-bucket CSR build + aggregate + W2 GEMM + tanh.
// (R8 structure; W2 staged from precomputed f16 global.)
// ---------------------------------------------------------------------------
__device__ __forceinline__ float4 relu4add(float4 acc, float4 a, float4 b) {
    acc.x += fmaxf(a.x + b.x, 0.f);
    acc.y += fmaxf(a.y + b.y, 0.f);
    acc.z += fmaxf(a.z + b.z, 0.f);
    acc.w += fmaxf(a.w + b.w, 0.f);
    return acc;
}
__device__ __forceinline__ float4 relu4add_m(float4 acc, float4 a, float4 b, bool m) {
    acc.x += m ? fmaxf(a.x + b.x, 0.f) : 0.f;
    acc.y += m ? fmaxf(a.y + b.y, 0.f) : 0.f;
    acc.z += m ? fmaxf(a.z + b.z, 0.f) : 0.f;
    acc.w += m ? fmaxf(a.w + b.w, 0.f) : 0.f;
    return acc;
}
__device__ __forceinline__ float4 bf4(uint2 u) {
    return make_float4(bf_lo(u.x), bf_hi(u.x), bf_lo(u.y), bf_hi(u.y));
}

__global__ __launch_bounds__(256) void fused_agg(
    const u16* __restrict__ Ah, const u16* __restrict__ Bmh,
    const u32* __restrict__ slotB, const int* __restrict__ gcnt,
    const u32* __restrict__ W2hg, const float* __restrict__ b2,
    float* __restrict__ out, int N)
{
    __shared__ __align__(16) u32 W2h[64][34];        // f16-packed W2, 8.7 KB
    __shared__ __align__(16) u32 pool[BN * 17 * 2];  // 17.4 KB: eStage then aggTb
    __shared__ u32 csrS[CAPB];                       // 8 KB
    __shared__ int histL[BN];
    __shared__ int rowO[BN + 1];
    __shared__ int ofs[BN];
    __shared__ float b2s[64];

    u32* eStage = pool;                              // [CAPB] (phase: CSR build)
    uint2* aggTb = (uint2*)pool;                     // [BN][17] (phase: agg)

    const int tid = threadIdx.x;
    const int b = blockIdx.x;
    const int node0 = b * BN;
    const int cntB = min(gcnt[b], CAPB);

    // Stage precomputed W2h: 2 uint4 per thread.
    {
        const uint4* Wg4 = (const uint4*)W2hg;
        #pragma unroll
        for (int it = 0; it < 2; ++it) {
            int i = it * 256 + tid;            // 0..511
            uint4 w = Wg4[i];
            *(uint4*)&W2h[i >> 3][(i & 7) * 4] = w;
        }
    }
    if (tid < 64) b2s[tid] = b2[tid];
    if (tid < BN) histL[tid] = 0;
    __syncthreads();

    for (int i = tid; i < cntB; i += 256) {
        u32 e = slotB[(size_t)b * CAPB + i];
        eStage[i] = e;
        atomicAdd(&histL[e >> 20], 1);
    }
    __syncthreads();

    if (tid < 64) {                                  // exclusive scan of 128 bins
        int l = tid;
        int h0 = histL[2 * l], h1 = histL[2 * l + 1];
        int s = h0 + h1, inc = s;
        #pragma unroll
        for (int off = 1; off < 64; off <<= 1) {
            int t = __shfl_up(inc, off);
            if (l >= off) inc += t;
        }
        int base = inc - s;
        rowO[2 * l] = base; rowO[2 * l + 1] = base + h0;
        ofs[2 * l] = base;  ofs[2 * l + 1] = base + h0;
        if (l == 63) rowO[BN] = inc;
    }
    __syncthreads();

    for (int i = tid; i < cntB; i += 256) {
        u32 e = eStage[i];
        int pos = atomicAdd(&ofs[e >> 20], 1);
        csrS[pos] = e & 0xFFFFFu;
    }
    __syncthreads();                                 // eStage dead; aggTb live

    // ---- Phase 1: gather-aggregate, 8 independent gathers per round ----
    {
        const int q = tid & 15, ng = tid >> 4;
        const uint2* __restrict__ B2 = (const uint2*)Bmh;
        const uint2* __restrict__ A2 = (const uint2*)Ah;
        #pragma unroll
        for (int h = 0; h < 8; ++h) {
            int nl = ng + h * 16;
            int gn = node0 + nl;
            int start = rowO[nl];
            int d = (gn < N) ? (rowO[nl + 1] - start) : 0;
            float4 a = make_float4(0.f, 0.f, 0.f, 0.f);
            if (gn < N) {
                uint2 ua = A2[(size_t)gn * 16 + q];
                a = make_float4(h_lo(ua.x), h_hi(ua.x), h_lo(ua.y), h_hi(ua.y));
            }
            float4 acc = make_float4(0.f, 0.f, 0.f, 0.f);

            int j = 0;
            for (; j + 8 <= d; j += 8) {             // exact 8-batches
                int ss[8];
                uint2 bb[8];
                #pragma unroll
                for (int t = 0; t < 8; ++t) ss[t] = csrS[start + j + t];
                #pragma unroll
                for (int t = 0; t < 8; ++t) bb[t] = B2[(size_t)ss[t] * 16 + q];
                #pragma unroll
                for (int t = 0; t < 8; ++t) acc = relu4add(acc, a, bf4(bb[t]));
            }
            if (j < d) {                             // masked 8-tail (clamped idx)
                int ss[8];
                uint2 bb[8];
                #pragma unroll
                for (int t = 0; t < 8; ++t) ss[t] = csrS[start + min(j + t, d - 1)];
                #pragma unroll
                for (int t = 0; t < 8; ++t) bb[t] = B2[(size_t)ss[t] * 16 + q];
                acc = relu4add(acc, a, bf4(bb[0]));
                #pragma unroll
                for (int t = 1; t < 8; ++t)
                    acc = relu4add_m(acc, a, bf4(bb[t]), j + t < d);
            }
            uint2 pk;
            pk.x = f2h(acc.x) | (f2h(acc.y) << 16);
            pk.y = f2h(acc.z) | (f2h(acc.w) << 16);
            aggTb[nl * 17 + q] = pk;
        }
    }
    __syncthreads();

    // ---- Phase 2: [128x64] @ W2 + deg*b2, tanh; W2 f16 from LDS ----
    {
        const int cg = tid & 15, g0 = tid >> 4;
        const int c0 = cg * 4;
        #pragma unroll
        for (int h = 0; h < 2; ++h) {
            int g = g0 + h * 16;       // 0..31
            int nb0 = g * 4;           // nodes nb0..nb0+3
            float o[4][4];
            #pragma unroll
            for (int ni = 0; ni < 4; ++ni) {
                float dg = (float)(rowO[nb0 + ni + 1] - rowO[nb0 + ni]);
                #pragma unroll
                for (int ci = 0; ci < 4; ++ci) o[ni][ci] = dg * b2s[c0 + ci];
            }
            #pragma unroll 2
            for (int kc = 0; kc < 16; ++kc) {
                uint2 u0 = aggTb[(nb0 + 0) * 17 + kc];
                uint2 u1 = aggTb[(nb0 + 1) * 17 + kc];
                uint2 u2 = aggTb[(nb0 + 2) * 17 + kc];
                uint2 u3 = aggTb[(nb0 + 3) * 17 + kc];
                #pragma unroll
                for (int kk = 0; kk < 4; ++kk) {
                    uint2 w2p = *(const uint2*)&W2h[kc * 4 + kk][cg * 2];
                    float wv[4] = {h_lo(w2p.x), h_hi(w2p.x), h_lo(w2p.y), h_hi(w2p.y)};
                    float a0 = (kk < 2) ? ((kk == 0) ? h_lo(u0.x) : h_hi(u0.x))
                                        : ((kk == 2) ? h_lo(u0.y) : h_hi(u0.y));
                    float a1 = (kk < 2) ? ((kk == 0) ? h_lo(u1.x) : h_hi(u1.x))
                                        : ((kk == 2) ? h_lo(u1.y) : h_hi(u1.y));
                    float a2 = (kk < 2) ? ((kk == 0) ? h_lo(u2.x) : h_hi(u2.x))
                                        : ((kk == 2) ? h_lo(u2.y) : h_hi(u2.y));
                    float a3 = (kk < 2) ? ((kk == 0) ? h_lo(u3.x) : h_hi(u3.x))
                                        : ((kk == 2) ? h_lo(u3.y) : h_hi(u3.y));
                    #pragma unroll
                    for (int ci = 0; ci < 4; ++ci) {
                        o[0][ci] += a0 * wv[ci];
                        o[1][ci] += a1 * wv[ci];
                        o[2][ci] += a2 * wv[ci];
                        o[3][ci] += a3 * wv[ci];
                    }
                }
            }
            #pragma unroll
            for (int ni = 0; ni < 4; ++ni) {
                int gn = node0 + nb0 + ni;
                if (gn < N) {
                    float4 r = make_float4(tanhf(o[ni][0]), tanhf(o[ni][1]),
                                           tanhf(o[ni][2]), tanhf(o[ni][3]));
                    ((float4*)out)[(size_t)gn * 16 + cg] = r;
                }
            }
        }
    }
}

// ---------------------------------------------------------------------------
extern "C" void kernel_launch(void* const* d_in, const int* in_sizes, int n_in,
                              void* d_out, int out_size, void* d_ws, size_t ws_size,
                              hipStream_t stream)
{
    const float* x  = (const float*)d_in[0];
    const int*   ei = (const int*)d_in[1];     // [2,E]: row0=src, row1=dst
    const float* W1 = (const float*)d_in[2];   // [128,64]
    const float* b1 = (const float*)d_in[3];   // [64]
    const float* W2 = (const float*)d_in[4];   // [64,64]
    const float* b2 = (const float*)d_in[5];   // [64]
    float* out = (float*)d_out;

    const int N = in_sizes[0] / FDIM;          // 100000
    const int E = in_sizes[1] / 2;             // 1200000
    const int NB = (N + BN - 1) / BN;          // 782 buckets

    // Workspace (re-poisoned 0xAA every call; gcnt zeroed below):
    u16*   Ah    = (u16*)d_ws;                          // N*64 f16  = 12.8 MB
    u16*   Bmh   = Ah + (size_t)N * FDIM;               // N*64 bf16 = 12.8 MB
    u32*   slotB = (u32*)(Bmh + (size_t)N * FDIM);      // NB*CAPB u32 = 6.4 MB
    u32*   Wchg  = slotB + (size_t)NB * CAPB;           // 4096 u32 (16 KB)
    u32*   W2hg  = Wchg + 4096;                         // 2048 u32 (8 KB)
    int*   gcnt  = (int*)(W2hg + 2048);                 // NB i32

    hipMemsetAsync(gcnt, 0, (size_t)NB * sizeof(int), stream);

    wprep_k<<<1, 256, 0, stream>>>(W1, W2, Wchg, W2hg);

    // Interleaved heterogeneous grid: 1 bin block per 6 (idx%6==5), rest pre.
    const int nPre = (N + 63) / 64;            // 1563
    const int nBin = (E + EPB - 1) / EPB;      // 293
    int T = (nPre * 6 + 4) / 5;
    while (T - T / 6 < nPre) ++T;
    if (T < 6 * nBin) T = 6 * nBin;

    prep_k<<<T, 256, 0, stream>>>(x, Wchg, b1, Ah, Bmh, ei, slotB, gcnt,
                                  N, E, NB, nPre, nBin);
    fused_agg<<<NB, 256, 0, stream>>>(Ah, Bmh, slotB, gcnt, W2hg, b2, out, N);
}